// Round 2
// baseline (440.997 us; speedup 1.0000x reference)
//
#include <hip/hip_runtime.h>
#include <hip/hip_bf16.h>
#include <stdint.h>

// Problem constants
constexpr int Bc = 8, Sc = 2048, Ec = 1024, Hc = 64;

typedef __bf16 bf16x8 __attribute__((ext_vector_type(8)));
typedef float f32x4 __attribute__((ext_vector_type(4)));
typedef unsigned short ushort8 __attribute__((ext_vector_type(8)));
typedef unsigned short ushort4v __attribute__((ext_vector_type(4)));

static __device__ __forceinline__ unsigned short f2bf(float f) {
  uint32_t u = __builtin_bit_cast(uint32_t, f);
  u = u + 0x7fffu + ((u >> 16) & 1u);   // round-to-nearest-even
  return (unsigned short)(u >> 16);
}
static __device__ __forceinline__ bf16x8 ldb8(const unsigned short* p) {
  return __builtin_bit_cast(bf16x8, *(const ushort8*)p);
}

// ---------------------------------------------------------------------------
// Kernel 0: W [E,H] fp32 -> Wt [3][H][E] bf16. Wq pre-scaled by 1/sqrt(H)=0.125
// (exact exponent shift in bf16) so attn needs no per-element scale.
// ---------------------------------------------------------------------------
__global__ __launch_bounds__(256) void wt_kernel(
    const float* __restrict__ Wq, const float* __restrict__ Wk,
    const float* __restrict__ Wv, unsigned short* __restrict__ Wt) {
  int idx = blockIdx.x * 256 + threadIdx.x;        // 0 .. 3*64*1024
  int m = idx >> 16;                                // /65536
  int r = idx & 65535;
  int h = r >> 10;
  int e = r & 1023;
  const float* W = (m == 0) ? Wq : (m == 1) ? Wk : Wv;
  float scale = (m == 0) ? 0.125f : 1.0f;
  Wt[idx] = f2bf(W[e * Hc + h] * scale);
}

// ---------------------------------------------------------------------------
// Kernel 1: projections. X [16384,1024] fp32 @ Wt^T -> bf16.
// block = 256 thr (4 waves); block tile = 16 rows x 64 cols; wave w does the
// 16-col n-tile nt=w (A-loads identical across waves -> L1 broadcast).
// grid (1024, 3) = 3072 blocks = 12 blocks/CU -> up to 32 waves/CU.
// Q,K stored row-major [s][h]; V stored transposed [b][h][s].
// ---------------------------------------------------------------------------
__global__ __launch_bounds__(256, 8) void proj_kernel(
    const float* __restrict__ Xq, const float* __restrict__ Xk,
    const float* __restrict__ Xv, const float* __restrict__ bq,
    const float* __restrict__ bk, const float* __restrict__ bv,
    const unsigned short* __restrict__ Wt,
    unsigned short* __restrict__ Qb, unsigned short* __restrict__ Kb,
    unsigned short* __restrict__ Vt) {
  const int mat = blockIdx.y;
  const float* X = (mat == 0) ? Xq : (mat == 1) ? Xk : Xv;
  const float* bias = (mat == 0) ? bq : (mat == 1) ? bk : bv;
  const float bscale = (mat == 0) ? 0.125f : 1.0f;
  const unsigned short* W = Wt + mat * (Hc * Ec);

  const int tid = threadIdx.x;
  const int wave = tid >> 6, lane = tid & 63;
  const int row0 = blockIdx.x * 16;
  const int arow = row0 + (lane & 15);
  const int kofs = (lane >> 4) * 8;

  const float* aptr = X + (size_t)arow * Ec + kofs;
  const unsigned short* wbase =
      W + (size_t)(wave * 16 + (lane & 15)) * Ec + kofs;

  f32x4 acc = (f32x4){0.f, 0.f, 0.f, 0.f};

  for (int kb = 0; kb < Ec; kb += 32) {
    float4 a0 = *(const float4*)(aptr + kb);
    float4 a1 = *(const float4*)(aptr + kb + 4);
    bf16x8 bfrag = ldb8(wbase + kb);
    ushort8 au;
    au[0] = f2bf(a0.x); au[1] = f2bf(a0.y); au[2] = f2bf(a0.z); au[3] = f2bf(a0.w);
    au[4] = f2bf(a1.x); au[5] = f2bf(a1.y); au[6] = f2bf(a1.z); au[7] = f2bf(a1.w);
    bf16x8 afrag = __builtin_bit_cast(bf16x8, au);
    acc = __builtin_amdgcn_mfma_f32_16x16x32_bf16(afrag, bfrag, acc, 0, 0, 0);
  }

  // Epilogue: C rows = row0 + (lane>>4)*4 + r, col = wave*16 + (lane&15).
  __shared__ unsigned short tile[16][72];
  {
    float bcol = bias[wave * 16 + (lane & 15)] * bscale;
#pragma unroll
    for (int r = 0; r < 4; r++)
      tile[(lane >> 4) * 4 + r][wave * 16 + (lane & 15)] = f2bf(acc[r] + bcol);
  }
  __syncthreads();

  if (mat < 2) {
    unsigned short* out = (mat == 0) ? Qb : Kb;
    int s_l = tid >> 4;              // 0..15
    int c0 = (tid & 15) * 4;         // 0..60
    ushort4v v = *(const ushort4v*)&tile[s_l][c0];
    *(ushort4v*)(out + (size_t)(row0 + s_l) * Hc + c0) = v;
  } else {
    // V transposed: Vt[b][h][s]
    int h = tid >> 2;                // 0..63
    int sc = (tid & 3) * 4;          // 0,4,8,12
    int bb = row0 >> 11;
    int sbase = (row0 & 2047) + sc;
    ushort4v v;
#pragma unroll
    for (int i = 0; i < 4; i++) v[i] = tile[sc + i][h];
    *(ushort4v*)(Vt + ((size_t)bb * Hc + h) * Sc + sbase) = v;
  }
}

// ---------------------------------------------------------------------------
// Kernel 2: flash-style attention, faithful mask->1e-10 semantics.
// grid (128, 8): blockIdx.y=b, blockIdx.x=q-tile of 16 rows. 4 waves each
// handle an independent 512-key range (online softmax), flash-combine in LDS.
// NO barriers in the K-loop; K/V read from global (L2-resident per batch).
// ---------------------------------------------------------------------------
__global__ __launch_bounds__(256, 4) void attn_kernel(
    const unsigned short* __restrict__ Qb, const unsigned short* __restrict__ Kb,
    const unsigned short* __restrict__ Vt, const int* __restrict__ mask,
    float* __restrict__ out) {
  const int b = blockIdx.y;
  const int q0 = blockIdx.x * 16;
  const int tid = threadIdx.x;
  const int wave = tid >> 6, lane = tid & 63;

  __shared__ unsigned short Ps[4][16][72];  // per-wave P staging (no barrier)
  __shared__ float sm[4][16], sl[4][16];
  __shared__ float Os[4][16][64];

  // Q A-fragments: rows q0..q0+15 (same for all waves; scale pre-folded)
  const unsigned short* qptr =
      Qb + ((size_t)b * Sc + q0 + (lane & 15)) * Hc + (lane >> 4) * 8;
  bf16x8 aQ0 = ldb8(qptr);
  bf16x8 aQ1 = ldb8(qptr + 32);

  // online-softmax state; C-layout rows: q0 + (lane>>4)*4 + r
  float m_r[4], l_r[4];
  f32x4 Oacc[4];
#pragma unroll
  for (int r = 0; r < 4; r++) { m_r[r] = -INFINITY; l_r[r] = 0.f; }
#pragma unroll
  for (int ht = 0; ht < 4; ht++) Oacc[ht] = (f32x4){0.f, 0.f, 0.f, 0.f};

  const int* mrow[4];
#pragma unroll
  for (int r = 0; r < 4; r++)
    mrow[r] = mask + ((size_t)b * Sc + q0 + (lane >> 4) * 4 + r) * Sc + (lane & 15);

  const unsigned short* kbase =
      Kb + ((size_t)b * Sc) * Hc + (size_t)(lane & 15) * Hc + (lane >> 4) * 8;
  const unsigned short* vbase[4];
#pragma unroll
  for (int ht = 0; ht < 4; ht++)
    vbase[ht] = Vt + ((size_t)b * Hc + ht * 16 + (lane & 15)) * Sc + (lane >> 4) * 8;

  for (int c = 0; c < 8; c++) {
    const int koff = wave * 512 + c * 64;

    // mask bits first (longest-latency loads, issue early)
    int mv[4][4];
#pragma unroll
    for (int nt = 0; nt < 4; nt++)
#pragma unroll
      for (int r = 0; r < 4; r++) mv[nt][r] = mrow[r][koff + nt * 16];

    // S = Q @ K^T (Q pre-scaled by 1/8)
    float sv[4][4];
#pragma unroll
    for (int nt = 0; nt < 4; nt++) {
      const unsigned short* kp = kbase + (size_t)(koff + nt * 16) * Hc;
      bf16x8 bK0 = ldb8(kp);
      bf16x8 bK1 = ldb8(kp + 32);
      f32x4 s = (f32x4){0.f, 0.f, 0.f, 0.f};
      s = __builtin_amdgcn_mfma_f32_16x16x32_bf16(aQ0, bK0, s, 0, 0, 0);
      s = __builtin_amdgcn_mfma_f32_16x16x32_bf16(aQ1, bK1, s, 0, 0, 0);
#pragma unroll
      for (int r = 0; r < 4; r++) sv[nt][r] = mv[nt][r] ? 1e-10f : s[r];
    }

    // row max across n-tiles then across the 16-lane group
    float rmax[4];
#pragma unroll
    for (int r = 0; r < 4; r++) {
      rmax[r] = fmaxf(fmaxf(sv[0][r], sv[1][r]), fmaxf(sv[2][r], sv[3][r]));
#pragma unroll
      for (int off = 1; off < 16; off <<= 1)
        rmax[r] = fmaxf(rmax[r], __shfl_xor(rmax[r], off, 64));
    }

    float alpha[4], p[4][4], psum[4];
#pragma unroll
    for (int r = 0; r < 4; r++) {
      float mnew = fmaxf(m_r[r], rmax[r]);
      alpha[r] = __expf(m_r[r] - mnew);
      m_r[r] = mnew;
      psum[r] = 0.f;
    }
#pragma unroll
    for (int nt = 0; nt < 4; nt++)
#pragma unroll
      for (int r = 0; r < 4; r++) {
        p[nt][r] = __expf(sv[nt][r] - m_r[r]);
        psum[r] += p[nt][r];
      }
#pragma unroll
    for (int r = 0; r < 4; r++) {
#pragma unroll
      for (int off = 1; off < 16; off <<= 1)
        psum[r] += __shfl_xor(psum[r], off, 64);
      l_r[r] = l_r[r] * alpha[r] + psum[r];
    }
#pragma unroll
    for (int ht = 0; ht < 4; ht++)
#pragma unroll
      for (int r = 0; r < 4; r++) Oacc[ht][r] *= alpha[r];

    // P: C-layout -> LDS -> A-layout (wave-private slab, no barrier needed)
#pragma unroll
    for (int nt = 0; nt < 4; nt++)
#pragma unroll
      for (int r = 0; r < 4; r++)
        Ps[wave][(lane >> 4) * 4 + r][nt * 16 + (lane & 15)] = f2bf(p[nt][r]);

    // O += P @ V
#pragma unroll
    for (int ks = 0; ks < 2; ks++) {
      bf16x8 aP = ldb8(&Ps[wave][lane & 15][ks * 32 + (lane >> 4) * 8]);
#pragma unroll
      for (int ht = 0; ht < 4; ht++) {
        bf16x8 bV = ldb8(vbase[ht] + koff + ks * 32);
        Oacc[ht] = __builtin_amdgcn_mfma_f32_16x16x32_bf16(aP, bV, Oacc[ht], 0, 0, 0);
      }
    }
  }

  // ---- flash combine across the 4 key-split waves ----
  if ((lane & 15) == 0) {
#pragma unroll
    for (int r = 0; r < 4; r++) {
      sm[wave][(lane >> 4) * 4 + r] = m_r[r];
      sl[wave][(lane >> 4) * 4 + r] = l_r[r];
    }
  }
  __syncthreads();

  float coef[4];
#pragma unroll
  for (int r = 0; r < 4; r++) {
    int row = (lane >> 4) * 4 + r;
    float M = fmaxf(fmaxf(sm[0][row], sm[1][row]), fmaxf(sm[2][row], sm[3][row]));
    coef[r] = __expf(m_r[r] - M);
  }
#pragma unroll
  for (int ht = 0; ht < 4; ht++)
#pragma unroll
    for (int r = 0; r < 4; r++)
      Os[wave][(lane >> 4) * 4 + r][ht * 16 + (lane & 15)] = Oacc[ht][r] * coef[r];
  __syncthreads();

  // wave w reduces rows [4w, 4w+4); col = lane
  {
#pragma unroll
    for (int i = 0; i < 4; i++) {
      int row = wave * 4 + i;
      float M = fmaxf(fmaxf(sm[0][row], sm[1][row]), fmaxf(sm[2][row], sm[3][row]));
      float L = sl[0][row] * __expf(sm[0][row] - M) +
                sl[1][row] * __expf(sm[1][row] - M) +
                sl[2][row] * __expf(sm[2][row] - M) +
                sl[3][row] * __expf(sm[3][row] - M);
      float acc = Os[0][row][lane] + Os[1][row][lane] +
                  Os[2][row][lane] + Os[3][row][lane];
      out[((size_t)b * Sc + q0 + row) * Hc + lane] = acc / L;
    }
  }
}

// ---------------------------------------------------------------------------
extern "C" void kernel_launch(void* const* d_in, const int* in_sizes, int n_in,
                              void* d_out, int out_size, void* d_ws, size_t ws_size,
                              hipStream_t stream) {
  const float* Xq = (const float*)d_in[0];
  const float* Xk = (const float*)d_in[1];
  const float* Xv = (const float*)d_in[2];
  const int* mask = (const int*)d_in[3];
  const float* Wq = (const float*)d_in[4];
  const float* bq = (const float*)d_in[5];
  const float* Wk = (const float*)d_in[6];
  const float* bk = (const float*)d_in[7];
  const float* Wv = (const float*)d_in[8];
  const float* bv = (const float*)d_in[9];

  unsigned short* Qb = (unsigned short*)d_ws;              // [16384][64] bf16
  unsigned short* Kb = Qb + (size_t)Bc * Sc * Hc;          // [16384][64] bf16
  unsigned short* Vt = Kb + (size_t)Bc * Sc * Hc;          // [8][64][2048] bf16
  unsigned short* Wt = Vt + (size_t)Bc * Sc * Hc;          // [3][64][1024] bf16

  wt_kernel<<<dim3(3 * Hc * Ec / 256), 256, 0, stream>>>(Wq, Wk, Wv, Wt);
  proj_kernel<<<dim3(Bc * Sc / 16, 3), 256, 0, stream>>>(Xq, Xk, Xv, bq, bk, bv,
                                                         Wt, Qb, Kb, Vt);
  attn_kernel<<<dim3(Sc / 16, Bc), 256, 0, stream>>>(Qb, Kb, Vt, mask,
                                                     (float*)d_out);
}

// Round 4
// 380.442 us; speedup vs baseline: 1.1592x; 1.1592x over previous
//
#include <hip/hip_runtime.h>
#include <hip/hip_bf16.h>
#include <stdint.h>

// Problem constants
constexpr int Bc = 8, Sc = 2048, Ec = 1024, Hc = 64;

typedef __bf16 bf16x8 __attribute__((ext_vector_type(8)));
typedef float f32x4 __attribute__((ext_vector_type(4)));
typedef unsigned short ushort8 __attribute__((ext_vector_type(8)));
typedef unsigned short ushort4v __attribute__((ext_vector_type(4)));

static __device__ __forceinline__ unsigned short f2bf(float f) {
  uint32_t u = __builtin_bit_cast(uint32_t, f);
  u = u + 0x7fffu + ((u >> 16) & 1u);   // round-to-nearest-even
  return (unsigned short)(u >> 16);
}
static __device__ __forceinline__ bf16x8 ldb8(const unsigned short* p) {
  return __builtin_bit_cast(bf16x8, *(const ushort8*)p);
}
static __device__ __forceinline__ uint32_t pk2bf(float a, float b) {
  return (uint32_t)f2bf(a) | ((uint32_t)f2bf(b) << 16);
}

// ---------------------------------------------------------------------------
// Kernel 0: W [E,H] fp32 -> Wt [3][H][E] bf16. Wq pre-scaled by 1/sqrt(H)=0.125
// (exact exponent shift in bf16) so attn needs no per-element scale.
// ---------------------------------------------------------------------------
__global__ __launch_bounds__(256) void wt_kernel(
    const float* __restrict__ Wq, const float* __restrict__ Wk,
    const float* __restrict__ Wv, unsigned short* __restrict__ Wt) {
  int idx = blockIdx.x * 256 + threadIdx.x;        // 0 .. 3*64*1024
  int m = idx >> 16;                                // /65536
  int r = idx & 65535;
  int h = r >> 10;
  int e = r & 1023;
  const float* W = (m == 0) ? Wq : (m == 1) ? Wk : Wv;
  float scale = (m == 0) ? 0.125f : 1.0f;
  Wt[idx] = f2bf(W[e * Hc + h] * scale);
}

// ---------------------------------------------------------------------------
// Kernel 1: projections, canonical LDS-staged MFMA GEMM.
// X [16384,1024] fp32 @ Wt[h][e] -> bf16. Block: 256 thr (4 waves),
// tile 64 rows x 64 cols (all H), BK=64, K-loop 16 chunks, 1-chunk reg
// prefetch. Coalesced X loads (16 lanes x float4 per row-segment),
// padded LDS (144 B rows, 16B-aligned).
// grid (256, 3) = 768 blocks = 3 blocks/CU, 12 waves/CU.
// Q,K stored row-major [s][h]; V stored transposed [b][h][s].
// ---------------------------------------------------------------------------
__global__ __launch_bounds__(256, 4) void proj_kernel(
    const float* __restrict__ Xq, const float* __restrict__ Xk,
    const float* __restrict__ Xv, const float* __restrict__ bq,
    const float* __restrict__ bk, const float* __restrict__ bv,
    const unsigned short* __restrict__ Wt,
    unsigned short* __restrict__ Qb, unsigned short* __restrict__ Kb,
    unsigned short* __restrict__ Vt) {
  const int mat = blockIdx.y;
  const float* X = (mat == 0) ? Xq : (mat == 1) ? Xk : Xv;
  const float* bias = (mat == 0) ? bq : (mat == 1) ? bk : bv;
  const float bscale = (mat == 0) ? 0.125f : 1.0f;
  const unsigned short* W = Wt + mat * (Hc * Ec);

  const int tid = threadIdx.x;
  const int wave = tid >> 6, lane = tid & 63;
  const int row0 = blockIdx.x * 64;

  __shared__ unsigned short As[64][72];   // 144 B rows: 16B-aligned, padded
  __shared__ unsigned short Ws[64][72];

  // X load mapping: pass p -> row p*16 + (tid>>4), cols (tid&15)*4 (+k0)
  const int xrow = tid >> 4;          // 0..15 (within 16-row slab)
  const int xcol = (tid & 15) * 4;    // 0..60
  const float* xptr = X + (size_t)(row0 + xrow) * Ec + xcol;

  // W load mapping: j = i*256+tid -> h = j>>3, kg = j&7 (128 B row-segments)
  float4 xr[4];
  ushort8 wr[2];

  auto load_chunk = [&](int c) {
    const int k0 = c * 64;
#pragma unroll
    for (int p = 0; p < 4; p++)
      xr[p] = *(const float4*)(xptr + (size_t)(p * 16) * Ec + k0);
#pragma unroll
    for (int i = 0; i < 2; i++) {
      int j = i * 256 + tid;
      int h = j >> 3, kg = j & 7;
      wr[i] = *(const ushort8*)(W + (size_t)h * Ec + k0 + kg * 8);
    }
  };

  f32x4 acc[4];
#pragma unroll
  for (int nt = 0; nt < 4; nt++) acc[nt] = (f32x4){0.f, 0.f, 0.f, 0.f};

  load_chunk(0);

  for (int c = 0; c < 16; c++) {
    // stage regs -> LDS (bf16)
#pragma unroll
    for (int p = 0; p < 4; p++) {
      ushort4v v = __builtin_bit_cast(
          ushort4v, (uint2){pk2bf(xr[p].x, xr[p].y), pk2bf(xr[p].z, xr[p].w)});
      *(ushort4v*)&As[p * 16 + xrow][xcol] = v;
    }
#pragma unroll
    for (int i = 0; i < 2; i++) {
      int j = i * 256 + tid;
      *(ushort8*)&Ws[j >> 3][(j & 7) * 8] = wr[i];
    }
    __syncthreads();

    if (c < 15) load_chunk(c + 1);  // overlap next chunk's loads with compute

    // compute: wave handles rows [wave*16, wave*16+16), all 64 cols
#pragma unroll
    for (int kk = 0; kk < 2; kk++) {
      bf16x8 aA = ldb8(&As[wave * 16 + (lane & 15)][kk * 32 + (lane >> 4) * 8]);
#pragma unroll
      for (int nt = 0; nt < 4; nt++) {
        bf16x8 bW = ldb8(&Ws[nt * 16 + (lane & 15)][kk * 32 + (lane >> 4) * 8]);
        acc[nt] = __builtin_amdgcn_mfma_f32_16x16x32_bf16(aA, bW, acc[nt], 0, 0, 0);
      }
    }
    __syncthreads();
  }

  // Epilogue: C tile (64x64) -> LDS (reuse As) -> coalesced stores.
  // C-layout: row = wave*16 + (lane>>4)*4 + r, col = nt*16 + (lane&15).
#pragma unroll
  for (int nt = 0; nt < 4; nt++) {
    float bcol = bias[nt * 16 + (lane & 15)] * bscale;
#pragma unroll
    for (int r = 0; r < 4; r++)
      As[wave * 16 + (lane >> 4) * 4 + r][nt * 16 + (lane & 15)] =
          f2bf(acc[nt][r] + bcol);
  }
  __syncthreads();

  if (mat < 2) {
    unsigned short* out = (mat == 0) ? Qb : Kb;
    int s_l = tid >> 2;
    int hs = (tid & 3) * 16;
    ushort8 v0 = *(const ushort8*)&As[s_l][hs];
    ushort8 v1 = *(const ushort8*)&As[s_l][hs + 8];
    unsigned short* dst = out + (size_t)(row0 + s_l) * Hc + hs;
    *(ushort8*)dst = v0;
    *(ushort8*)(dst + 8) = v1;
  } else {
    // V transposed: Vt[b][h][s]
    int h = tid >> 2;
    int ss = (tid & 3) * 16;
    int bb = row0 >> 11;                 // block never straddles a batch
    int sbase = (row0 & 2047) + ss;
    ushort8 v0, v1;
#pragma unroll
    for (int i = 0; i < 8; i++) {
      v0[i] = As[ss + i][h];
      v1[i] = As[ss + 8 + i][h];
    }
    unsigned short* dst = Vt + ((size_t)bb * Hc + h) * Sc + sbase;
    *(ushort8*)dst = v0;
    *(ushort8*)(dst + 8) = v1;
  }
}

// ---------------------------------------------------------------------------
// Kernel 2: flash-style attention, faithful mask->1e-10 semantics.
// grid (128, 8): blockIdx.y=b, blockIdx.x=q-tile of 16 rows. 4 waves each
// handle an independent 512-key range (online softmax), flash-combine in LDS.
// NO barriers in the K-loop; K/V read from global (L2-resident per batch).
// ---------------------------------------------------------------------------
__global__ __launch_bounds__(256, 4) void attn_kernel(
    const unsigned short* __restrict__ Qb, const unsigned short* __restrict__ Kb,
    const unsigned short* __restrict__ Vt, const int* __restrict__ mask,
    float* __restrict__ out) {
  const int b = blockIdx.y;
  const int q0 = blockIdx.x * 16;
  const int tid = threadIdx.x;
  const int wave = tid >> 6, lane = tid & 63;

  __shared__ unsigned short Ps[4][16][72];  // per-wave P staging (no barrier)
  __shared__ float sm[4][16], sl[4][16];
  __shared__ float Os[4][16][64];

  // Q A-fragments: rows q0..q0+15 (same for all waves; scale pre-folded)
  const unsigned short* qptr =
      Qb + ((size_t)b * Sc + q0 + (lane & 15)) * Hc + (lane >> 4) * 8;
  bf16x8 aQ0 = ldb8(qptr);
  bf16x8 aQ1 = ldb8(qptr + 32);

  // online-softmax state; C-layout rows: q0 + (lane>>4)*4 + r
  float m_r[4], l_r[4];
  f32x4 Oacc[4];
#pragma unroll
  for (int r = 0; r < 4; r++) { m_r[r] = -INFINITY; l_r[r] = 0.f; }
#pragma unroll
  for (int ht = 0; ht < 4; ht++) Oacc[ht] = (f32x4){0.f, 0.f, 0.f, 0.f};

  const int* mrow[4];
#pragma unroll
  for (int r = 0; r < 4; r++)
    mrow[r] = mask + ((size_t)b * Sc + q0 + (lane >> 4) * 4 + r) * Sc + (lane & 15);

  const unsigned short* kbase =
      Kb + ((size_t)b * Sc) * Hc + (size_t)(lane & 15) * Hc + (lane >> 4) * 8;
  const unsigned short* vbase[4];
#pragma unroll
  for (int ht = 0; ht < 4; ht++)
    vbase[ht] = Vt + ((size_t)b * Hc + ht * 16 + (lane & 15)) * Sc + (lane >> 4) * 8;

  for (int c = 0; c < 8; c++) {
    const int koff = wave * 512 + c * 64;

    // mask bits first (longest-latency loads, issue early)
    int mv[4][4];
#pragma unroll
    for (int nt = 0; nt < 4; nt++)
#pragma unroll
      for (int r = 0; r < 4; r++) mv[nt][r] = mrow[r][koff + nt * 16];

    // S = Q @ K^T (Q pre-scaled by 1/8)
    float sv[4][4];
#pragma unroll
    for (int nt = 0; nt < 4; nt++) {
      const unsigned short* kp = kbase + (size_t)(koff + nt * 16) * Hc;
      bf16x8 bK0 = ldb8(kp);
      bf16x8 bK1 = ldb8(kp + 32);
      f32x4 s = (f32x4){0.f, 0.f, 0.f, 0.f};
      s = __builtin_amdgcn_mfma_f32_16x16x32_bf16(aQ0, bK0, s, 0, 0, 0);
      s = __builtin_amdgcn_mfma_f32_16x16x32_bf16(aQ1, bK1, s, 0, 0, 0);
#pragma unroll
      for (int r = 0; r < 4; r++) sv[nt][r] = mv[nt][r] ? 1e-10f : s[r];
    }

    // row max across n-tiles then across the 16-lane group
    float rmax[4];
#pragma unroll
    for (int r = 0; r < 4; r++) {
      rmax[r] = fmaxf(fmaxf(sv[0][r], sv[1][r]), fmaxf(sv[2][r], sv[3][r]));
#pragma unroll
      for (int off = 1; off < 16; off <<= 1)
        rmax[r] = fmaxf(rmax[r], __shfl_xor(rmax[r], off, 64));
    }

    float alpha[4], p[4][4], psum[4];
#pragma unroll
    for (int r = 0; r < 4; r++) {
      float mnew = fmaxf(m_r[r], rmax[r]);
      alpha[r] = __expf(m_r[r] - mnew);
      m_r[r] = mnew;
      psum[r] = 0.f;
    }
#pragma unroll
    for (int nt = 0; nt < 4; nt++)
#pragma unroll
      for (int r = 0; r < 4; r++) {
        p[nt][r] = __expf(sv[nt][r] - m_r[r]);
        psum[r] += p[nt][r];
      }
#pragma unroll
    for (int r = 0; r < 4; r++) {
#pragma unroll
      for (int off = 1; off < 16; off <<= 1)
        psum[r] += __shfl_xor(psum[r], off, 64);
      l_r[r] = l_r[r] * alpha[r] + psum[r];
    }
#pragma unroll
    for (int ht = 0; ht < 4; ht++)
#pragma unroll
      for (int r = 0; r < 4; r++) Oacc[ht][r] *= alpha[r];

    // P: C-layout -> LDS -> A-layout (wave-private slab, no barrier needed)
#pragma unroll
    for (int nt = 0; nt < 4; nt++)
#pragma unroll
      for (int r = 0; r < 4; r++)
        Ps[wave][(lane >> 4) * 4 + r][nt * 16 + (lane & 15)] = f2bf(p[nt][r]);

    // O += P @ V
#pragma unroll
    for (int ks = 0; ks < 2; ks++) {
      bf16x8 aP = ldb8(&Ps[wave][lane & 15][ks * 32 + (lane >> 4) * 8]);
#pragma unroll
      for (int ht = 0; ht < 4; ht++) {
        bf16x8 bV = ldb8(vbase[ht] + koff + ks * 32);
        Oacc[ht] = __builtin_amdgcn_mfma_f32_16x16x32_bf16(aP, bV, Oacc[ht], 0, 0, 0);
      }
    }
  }

  // ---- flash combine across the 4 key-split waves ----
  if ((lane & 15) == 0) {
#pragma unroll
    for (int r = 0; r < 4; r++) {
      sm[wave][(lane >> 4) * 4 + r] = m_r[r];
      sl[wave][(lane >> 4) * 4 + r] = l_r[r];
    }
  }
  __syncthreads();

  float coef[4];
#pragma unroll
  for (int r = 0; r < 4; r++) {
    int row = (lane >> 4) * 4 + r;
    float M = fmaxf(fmaxf(sm[0][row], sm[1][row]), fmaxf(sm[2][row], sm[3][row]));
    coef[r] = __expf(m_r[r] - M);
  }
#pragma unroll
  for (int ht = 0; ht < 4; ht++)
#pragma unroll
    for (int r = 0; r < 4; r++)
      Os[wave][(lane >> 4) * 4 + r][ht * 16 + (lane & 15)] = Oacc[ht][r] * coef[r];
  __syncthreads();

  // wave w reduces rows [4w, 4w+4); col = lane
  {
#pragma unroll
    for (int i = 0; i < 4; i++) {
      int row = wave * 4 + i;
      float M = fmaxf(fmaxf(sm[0][row], sm[1][row]), fmaxf(sm[2][row], sm[3][row]));
      float L = sl[0][row] * __expf(sm[0][row] - M) +
                sl[1][row] * __expf(sm[1][row] - M) +
                sl[2][row] * __expf(sm[2][row] - M) +
                sl[3][row] * __expf(sm[3][row] - M);
      float acc = Os[0][row][lane] + Os[1][row][lane] +
                  Os[2][row][lane] + Os[3][row][lane];
      out[((size_t)b * Sc + q0 + row) * Hc + lane] = acc / L;
    }
  }
}

// ---------------------------------------------------------------------------
extern "C" void kernel_launch(void* const* d_in, const int* in_sizes, int n_in,
                              void* d_out, int out_size, void* d_ws, size_t ws_size,
                              hipStream_t stream) {
  const float* Xq = (const float*)d_in[0];
  const float* Xk = (const float*)d_in[1];
  const float* Xv = (const float*)d_in[2];
  const int* mask = (const int*)d_in[3];
  const float* Wq = (const float*)d_in[4];
  const float* bq = (const float*)d_in[5];
  const float* Wk = (const float*)d_in[6];
  const float* bk = (const float*)d_in[7];
  const float* Wv = (const float*)d_in[8];
  const float* bv = (const float*)d_in[9];

  unsigned short* Qb = (unsigned short*)d_ws;              // [16384][64] bf16
  unsigned short* Kb = Qb + (size_t)Bc * Sc * Hc;          // [16384][64] bf16
  unsigned short* Vt = Kb + (size_t)Bc * Sc * Hc;          // [8][64][2048] bf16
  unsigned short* Wt = Vt + (size_t)Bc * Sc * Hc;          // [3][64][1024] bf16

  wt_kernel<<<dim3(3 * Hc * Ec / 256), 256, 0, stream>>>(Wq, Wk, Wv, Wt);
  proj_kernel<<<dim3(Bc * Sc / 64, 3), 256, 0, stream>>>(Xq, Xk, Xv, bq, bk, bv,
                                                         Wt, Qb, Kb, Vt);
  attn_kernel<<<dim3(Sc / 16, Bc), 256, 0, stream>>>(Qb, Kb, Vt, mask,
                                                     (float*)d_out);
}